// Round 6
// baseline (533.940 us; speedup 1.0000x reference)
//
#include <hip/hip_runtime.h>
#include <hip/hip_bf16.h>

typedef __bf16 bf16x8 __attribute__((ext_vector_type(8)));
typedef float  f32x4  __attribute__((ext_vector_type(4)));

#define BSZ 8192

// ---------------- prep: convert w1/w2 to bf16 in GEMM layout [oc][k] ----------------
// k ordering: k = (dy*2+dx)*C + c   (c fastest)
__global__ void k_prep(const float* __restrict__ w1, const float* __restrict__ w2,
                       __bf16* __restrict__ w1b, __bf16* __restrict__ w2b) {
    int t = blockIdx.x * blockDim.x + threadIdx.x;
    if (t < 8192) {           // w1: 64 oc x 128 k
        int oc = t >> 7, k = t & 127, c = k & 31, d = k >> 5;
        w1b[t] = (__bf16)w1[oc * 128 + c * 4 + d];
    }
    if (t < 32768) {          // w2: 128 oc x 256 k
        int oc = t >> 8, k = t & 255, c = k & 63, d = k >> 6;
        w2b[t] = (__bf16)w2[oc * 256 + c * 4 + d];
    }
}

// ---------------- stats0 via 9x9 second-moment matrix (channel-independent) ----------------
__global__ __launch_bounds__(256) void k_stats0(const float* __restrict__ x,
                                                float* __restrict__ part0) {
    __shared__ float sred[4 * 54];
    const int tid = threadIdx.x;
    float a[54];
#pragma unroll
    for (int i = 0; i < 54; i++) a[i] = 0.f;
    const int total = BSZ * 784;
    for (int p = blockIdx.x * 256 + tid; p < total; p += gridDim.x * 256) {
        int b = p / 784, pix = p - b * 784;
        int y = pix / 28, xx = pix - y * 28;
        const float* xb = x + (long)b * 784;
        float nv[9];
#pragma unroll
        for (int dy = 0; dy < 3; dy++) {
            int yy = y + dy - 1;
#pragma unroll
            for (int dx = 0; dx < 3; dx++) {
                int x2 = xx + dx - 1;
                nv[dy * 3 + dx] = (yy >= 0 && yy < 28 && x2 >= 0 && x2 < 28) ? xb[yy * 28 + x2] : 0.f;
            }
        }
        int idx = 0;
#pragma unroll
        for (int t = 0; t < 9; t++) {
            float vt = nv[t];
            a[45 + t] += vt;
#pragma unroll
            for (int u = t; u < 9; u++) { a[idx] += vt * nv[u]; idx++; }
        }
    }
#pragma unroll
    for (int i = 0; i < 54; i++) {
        float v = a[i];
        v += __shfl_xor(v, 1);  v += __shfl_xor(v, 2);  v += __shfl_xor(v, 4);
        v += __shfl_xor(v, 8);  v += __shfl_xor(v, 16); v += __shfl_xor(v, 32);
        a[i] = v;
    }
    const int l = tid & 63, w = tid >> 6;
    if (l == 0) {
#pragma unroll
        for (int i = 0; i < 54; i++) sred[w * 54 + i] = a[i];
    }
    __syncthreads();
    if (tid < 54)
        part0[blockIdx.x * 64 + tid] = sred[tid] + sred[54 + tid] + sred[108 + tid] + sred[162 + tid];
}

// finalize BN0 and fold into conv0 weights: abc0[pg*72 + tap*8 + j] = A0[c]*w0[c][tap],
// abc0[288 + c] = C0[c]  (c = pg*8 + j)
__global__ void k_fin0(const float* __restrict__ part0, const float* __restrict__ w0,
                       const float* __restrict__ g0, const float* __restrict__ be0,
                       float* __restrict__ abc0) {
    __shared__ float red[4 * 54];
    int t = threadIdx.x, c = t & 63, g = t >> 6;
    if (c < 54) {
        float acc = 0.f;
        for (int i = g; i < 1024; i += 4) acc += part0[i * 64 + c];
        red[g * 54 + c] = acc;
    }
    __syncthreads();
    if (t < 54) red[t] = red[t] + red[54 + t] + red[108 + t] + red[162 + t];
    __syncthreads();
    if (t < 32) {
        float wv[9];
#pragma unroll
        for (int tap = 0; tap < 9; tap++) wv[tap] = w0[t * 9 + tap];
        float sum = 0.f, sq = 0.f;
        int idx = 0;
#pragma unroll
        for (int ta = 0; ta < 9; ta++) {
            sum = fmaf(wv[ta], red[45 + ta], sum);
#pragma unroll
            for (int u = ta; u < 9; u++) {
                float coef = (u == ta) ? 1.f : 2.f;
                sq = fmaf(coef * wv[ta] * wv[u], red[idx], sq);
                idx++;
            }
        }
        float cnt = (float)BSZ * 784.f;
        float mean = sum / cnt;
        float var = sq / cnt - mean * mean;
        float A = g0[t] * rsqrtf(var + 1e-5f);
#pragma unroll
        for (int tap = 0; tap < 9; tap++)
            abc0[(t >> 3) * 72 + tap * 8 + (t & 7)] = A * wv[tap];
        abc0[288 + t] = be0[t] - mean * A;
    }
}

// ---------------- fused conv0(+BN0 folded)+ReLU + MFMA conv1, streamed 16-row tiles ----------------
// double-buffered tile: 16 rows x 128 k, row stride 136 elem. One barrier/tile.
// producer: tid -> (row i = tid&15, sub-pixel d = (tid>>4)&3, channel-group pg = tid>>6).
// pg == wave id -> folded weights loaded via wave-uniform (scalar) loads.
__global__ __launch_bounds__(256) void k_conv01(const float* __restrict__ x,
                                                const float* __restrict__ abc0,
                                                const __bf16* __restrict__ w1b,
                                                __bf16* __restrict__ h1,
                                                float* __restrict__ part1) {
    __shared__ float xs[30 * 30];     // zero-padded input
    __shared__ __attribute__((aligned(16))) __bf16 sAt[2][16 * 136];
    const int b = blockIdx.x, tid = threadIdx.x;
    // zero border (116 cells)
    if (tid < 116) {
        int idx;
        if (tid < 30)      idx = tid;
        else if (tid < 60) idx = 29 * 30 + (tid - 30);
        else if (tid < 88) idx = (tid - 60 + 1) * 30;
        else               idx = (tid - 88 + 1) * 30 + 29;
        xs[idx] = 0.f;
    }
    for (int j = tid; j < 784; j += 256) {
        int yy = j / 28, xx2 = j - yy * 28;
        xs[(yy + 1) * 30 + xx2 + 1] = x[(long)b * 784 + j];
    }
    // hoisted folded weights (wave-uniform -> scalar regs)
    const int pgu = __builtin_amdgcn_readfirstlane(tid >> 6);
    const float* wfp = abc0 + pgu * 72;
    float wf[72];
#pragma unroll
    for (int i = 0; i < 72; i++) wf[i] = wfp[i];
    float c0r[8];
#pragma unroll
    for (int j = 0; j < 8; j++) c0r[j] = abc0[288 + pgu * 8 + j];

    // producer indices
    const int pi = tid & 15, pd = (tid >> 4) & 3;
    // consumer indices
    const int w = tid >> 6, l = tid & 63, q = l >> 4, n = l & 15;
    const int oc = w * 16 + n;
    bf16x8 fbv[4];
#pragma unroll
    for (int kc = 0; kc < 4; kc++)
        fbv[kc] = *(const bf16x8*)&w1b[oc * 128 + kc * 32 + q * 8];
    float ssum = 0.f, ssq = 0.f;
    __bf16* hb = h1 + (long)b * 12544 + (q * 4) * 64 + oc;
    __syncthreads();

    for (int mt = 0; mt < 13; mt++) {
        // ---- produce tile mt into sAt[mt&1] ----
        __bf16* dst = &sAt[mt & 1][pi * 136 + pd * 32 + pgu * 8];
        int m = mt * 16 + pi;
        bf16x8 pk;
        if (m < 196) {
            int my = m / 14, mx = m - my * 14;
            int y0 = my * 2 + (pd >> 1), x0 = mx * 2 + (pd & 1);
            float nv[9];
#pragma unroll
            for (int dy = 0; dy < 3; dy++)
#pragma unroll
                for (int dx = 0; dx < 3; dx++)
                    nv[dy * 3 + dx] = xs[(y0 + dy) * 30 + x0 + dx];
            float a[8];
#pragma unroll
            for (int j = 0; j < 8; j++) a[j] = c0r[j];
#pragma unroll
            for (int t = 0; t < 9; t++) {
                float nvt = nv[t];
#pragma unroll
                for (int j = 0; j < 8; j++) a[j] = fmaf(nvt, wf[t * 8 + j], a[j]);
            }
#pragma unroll
            for (int j = 0; j < 8; j++) pk[j] = (__bf16)fmaxf(a[j], 0.f);
        } else {
#pragma unroll
            for (int j = 0; j < 8; j++) pk[j] = (__bf16)0.0f;
        }
        *(bf16x8*)dst = pk;
        __syncthreads();
        // ---- consume tile mt ----
        const __bf16* sa = &sAt[mt & 1][n * 136 + q * 8];
        f32x4 acc = {0.f, 0.f, 0.f, 0.f};
#pragma unroll
        for (int kc = 0; kc < 4; kc++) {
            bf16x8 fav = *(const bf16x8*)&sa[kc * 32];
            acc = __builtin_amdgcn_mfma_f32_16x16x32_bf16(fav, fbv[kc], acc, 0, 0, 0);
        }
        bool valid = (mt < 12) | (q == 0);
        __bf16* hp = hb + mt * 16 * 64;
#pragma unroll
        for (int r = 0; r < 4; r++) {
            __bf16 hv = (__bf16)acc[r];
            if (valid) hp[r * 64] = hv;
            float fv = (float)hv;               // padded rows give 0 -> no stat effect
            ssum += fv; ssq += fv * fv;
        }
    }
    ssum += __shfl_xor(ssum, 16); ssum += __shfl_xor(ssum, 32);
    ssq  += __shfl_xor(ssq, 16);  ssq  += __shfl_xor(ssq, 32);
    if (l < 16) {
        part1[(long)oc * BSZ + b] = ssum;
        part1[(long)(64 + oc) * BSZ + b] = ssq;
    }
}

// ---------------- generic column reducer + BN finalizer ----------------
__global__ void k_red(const float* __restrict__ part, float* __restrict__ red, int rows) {
    __shared__ float sred[256];
    int c = blockIdx.x;
    float a = 0.f;
    for (int i = threadIdx.x; i < rows; i += 256) a += part[(long)c * rows + i];
    sred[threadIdx.x] = a;
    __syncthreads();
    for (int s = 128; s > 0; s >>= 1) {
        if (threadIdx.x < s) sred[threadIdx.x] += sred[threadIdx.x + s];
        __syncthreads();
    }
    if (threadIdx.x == 0) red[c] = sred[0];
}

__global__ void k_fin(const float* __restrict__ red, const float* __restrict__ g,
                      const float* __restrict__ be, float* __restrict__ abc,
                      int C, float cnt) {
    int t = threadIdx.x;
    if (t < C) {
        float mean = red[t] / cnt;
        float var = red[C + t] / cnt - mean * mean;
        float A = g[t] * rsqrtf(var + 1e-5f);
        abc[t] = A;
        abc[C + t] = be[t] - mean * A;
    }
}

// ---------------- conv2 MFMA, register-staged A (BN1+ReLU in-reg) -> z2 (aliased into h1) + stats2 ----------------
// No LDS. Per-mt: all waves load A-frags direct from h1 (L1 serves 4x redundancy),
// barrier (drains vmcnt), then MFMA + z2 writes. Alias safety: writes(<=mt) touch h1 rows
// < (mt+1)*32; loads(mt+1) touch rows >= 60/120/180 -> disjoint.
__global__ __launch_bounds__(256) void k_conv2s(__bf16* __restrict__ h1,
                                                const __bf16* __restrict__ w2b,
                                                const float* __restrict__ abc1,
                                                float* __restrict__ part2) {
    const int b = blockIdx.x, tid = threadIdx.x;
    const int w = tid >> 6, l = tid & 63, q = l >> 4, n = l & 15;
    float bnA[16], bnC[16];   // [j]=c lo (q*8+j), [8+j]=c hi (32+q*8+j)
#pragma unroll
    for (int j = 0; j < 8; j++) {
        bnA[j]     = abc1[q * 8 + j];
        bnA[8 + j] = abc1[32 + q * 8 + j];
        bnC[j]     = abc1[64 + q * 8 + j];
        bnC[8 + j] = abc1[96 + q * 8 + j];
    }
    bf16x8 fbv[2][8];
#pragma unroll
    for (int ntl = 0; ntl < 2; ntl++) {
        int oc = (2 * w + ntl) * 16 + n;
#pragma unroll
        for (int kc = 0; kc < 8; kc++)
            fbv[ntl][kc] = *(const bf16x8*)&w2b[oc * 256 + kc * 32 + q * 8];
    }
    __bf16* base = h1 + (long)b * 12544;
    float ssum[2] = {0.f, 0.f}, ssq[2] = {0.f, 0.f};
    for (int mt = 0; mt < 4; mt++) {
        int r = mt * 16 + n;
        bf16x8 fav[8];
        if (r < 49) {
            int py = r / 7, px = r - py * 7;
#pragma unroll
            for (int kc = 0; kc < 8; kc++) {
                int d = kc >> 1;
                int msrc = (2 * py + (d >> 1)) * 14 + 2 * px + (d & 1);
                int c0 = (kc & 1) * 32 + q * 8;
                bf16x8 v = *(const bf16x8*)&base[msrc * 64 + c0];
                int bo = (kc & 1) * 8;
#pragma unroll
                for (int j = 0; j < 8; j++) {
                    float f = fmaxf((float)v[j] * bnA[bo + j] + bnC[bo + j], 0.f);
                    fav[kc][j] = (__bf16)f;
                }
            }
        } else {
#pragma unroll
            for (int kc = 0; kc < 8; kc++)
#pragma unroll
                for (int j = 0; j < 8; j++) fav[kc][j] = (__bf16)0.0f;
        }
        __syncthreads();   // drains vmcnt(0): all tile-mt loads serviced before any z2 write below
#pragma unroll
        for (int ntl = 0; ntl < 2; ntl++) {
            f32x4 acc = {0.f, 0.f, 0.f, 0.f};
#pragma unroll
            for (int kc = 0; kc < 8; kc++)
                acc = __builtin_amdgcn_mfma_f32_16x16x32_bf16(fav[kc], fbv[ntl][kc], acc, 0, 0, 0);
#pragma unroll
            for (int rr = 0; rr < 4; rr++) {
                __bf16 hv = (__bf16)acc[rr];
                int m = mt * 16 + q * 4 + rr;
                if (m < 49) base[m * 128 + (2 * w + ntl) * 16 + n] = hv;
                float fv = (float)hv;           // padded rows -> 0
                ssum[ntl] += fv; ssq[ntl] += fv * fv;
            }
        }
    }
#pragma unroll
    for (int ntl = 0; ntl < 2; ntl++) {
        ssum[ntl] += __shfl_xor(ssum[ntl], 16); ssum[ntl] += __shfl_xor(ssum[ntl], 32);
        ssq[ntl]  += __shfl_xor(ssq[ntl], 16);  ssq[ntl]  += __shfl_xor(ssq[ntl], 32);
    }
    if (l < 16) {
#pragma unroll
        for (int ntl = 0; ntl < 2; ntl++) {
            int oc = (2 * w + ntl) * 16 + l;
            part2[(long)oc * BSZ + b] = ssum[ntl];
            part2[(long)(128 + oc) * BSZ + b] = ssq[ntl];
        }
    }
}

// ---------------- light epilogue: BN2 + ReLU + avgpool + FC from z2 ----------------
__global__ __launch_bounds__(256) void k_final(const __bf16* __restrict__ z2,
                                               const float* __restrict__ abc2,
                                               const float* __restrict__ wfc,
                                               const float* __restrict__ bfc,
                                               float* __restrict__ out) {
    __shared__ float sbn2[256];
    __shared__ float pp[16 * 128];
    __shared__ float pooled[128];
    __shared__ float fcred[80];
    const int b = blockIdx.x, tid = threadIdx.x;
    sbn2[tid] = abc2[tid];
    __syncthreads();
    const int g = tid & 15, c0 = g * 8, rg = tid >> 4;
    const __bf16* src = z2 + (long)b * 12544;
    float acc[8];
#pragma unroll
    for (int q = 0; q < 8; q++) acc[q] = 0.f;
    for (int rr = rg; rr < 49; rr += 16) {
        bf16x8 v = *(const bf16x8*)&src[rr * 128 + c0];
#pragma unroll
        for (int q = 0; q < 8; q++) {
            float f = fmaxf((float)v[q] * sbn2[c0 + q] + sbn2[128 + c0 + q], 0.f);
            acc[q] += f;
        }
    }
    *(f32x4*)&pp[rg * 128 + c0]     = *(f32x4*)&acc[0];
    *(f32x4*)&pp[rg * 128 + c0 + 4] = *(f32x4*)&acc[4];
    __syncthreads();
    if (tid < 128) {
        float s = 0.f;
#pragma unroll
        for (int r = 0; r < 16; r++) s += pp[r * 128 + tid];
        pooled[tid] = s * (1.f / 49.f);
    }
    __syncthreads();
    if (tid < 80) {
        int o = tid >> 3, s = tid & 7;
        float a = 0.f;
#pragma unroll
        for (int j = 0; j < 16; j++) a = fmaf(pooled[s * 16 + j], wfc[o * 128 + s * 16 + j], a);
        fcred[tid] = a;
    }
    __syncthreads();
    if (tid < 10) {
        float a = bfc[tid];
#pragma unroll
        for (int s = 0; s < 8; s++) a += fcred[tid * 8 + s];
        out[(long)b * 10 + tid] = a;
    }
}

extern "C" void kernel_launch(void* const* d_in, const int* in_sizes, int n_in,
                              void* d_out, int out_size, void* d_ws, size_t ws_size,
                              hipStream_t stream) {
    const float* x   = (const float*)d_in[0];
    const float* w0  = (const float*)d_in[1];
    const float* g0  = (const float*)d_in[3];
    const float* be0 = (const float*)d_in[4];
    const float* w1  = (const float*)d_in[5];
    const float* g1  = (const float*)d_in[7];
    const float* be1 = (const float*)d_in[8];
    const float* w2  = (const float*)d_in[9];
    const float* g2  = (const float*)d_in[11];
    const float* be2 = (const float*)d_in[12];
    const float* wfc = (const float*)d_in[13];
    const float* bfc = (const float*)d_in[14];
    float* out = (float*)d_out;

    float* ws    = (float*)d_ws;
    float* part0 = ws;                       // 1024*64
    float* abc0  = part0 + 1024 * 64;        // 320 (folded w + C0)
    float* part1 = abc0 + 320;               // 128*8192
    float* red1  = part1 + 128 * BSZ;        // 128
    float* abc1  = red1 + 128;               // 128
    float* part2 = abc1 + 128;               // 256*8192
    float* red2  = part2 + 256 * BSZ;        // 256
    float* abc2  = red2 + 256;               // 256
    __bf16* w1b  = (__bf16*)(abc2 + 256);    // 8192
    __bf16* w2b  = w1b + 8192;               // 32768
    __bf16* h1   = w2b + 32768;              // 8192*12544 bf16 (~205 MB); z2 aliased per-image

    k_prep<<<dim3(128), dim3(256), 0, stream>>>(w1, w2, w1b, w2b);
    k_stats0<<<dim3(1024), dim3(256), 0, stream>>>(x, part0);
    k_fin0<<<dim3(1), dim3(256), 0, stream>>>(part0, w0, g0, be0, abc0);
    k_conv01<<<dim3(BSZ), dim3(256), 0, stream>>>(x, abc0, w1b, h1, part1);
    k_red<<<dim3(128), dim3(256), 0, stream>>>(part1, red1, BSZ);
    k_fin<<<dim3(1), dim3(64), 0, stream>>>(red1, g1, be1, abc1, 64, (float)(BSZ * 196));
    k_conv2s<<<dim3(BSZ), dim3(256), 0, stream>>>(h1, w2b, abc1, part2);
    k_red<<<dim3(256), dim3(256), 0, stream>>>(part2, red2, BSZ);
    k_fin<<<dim3(1), dim3(128), 0, stream>>>(red2, g2, be2, abc2, 128, (float)(BSZ * 49));
    k_final<<<dim3(BSZ), dim3(256), 0, stream>>>(h1, abc2, wfc, bfc, out);
}

// Round 7
// 431.247 us; speedup vs baseline: 1.2381x; 1.2381x over previous
//
#include <hip/hip_runtime.h>
#include <hip/hip_bf16.h>

typedef __bf16 bf16x8 __attribute__((ext_vector_type(8)));
typedef float  f32x4  __attribute__((ext_vector_type(4)));

#define BSZ 8192

// ---------------- prep: convert w1/w2 to bf16 in GEMM layout [oc][k] ----------------
// k ordering: k = (dy*2+dx)*C + c   (c fastest)
__global__ void k_prep(const float* __restrict__ w1, const float* __restrict__ w2,
                       __bf16* __restrict__ w1b, __bf16* __restrict__ w2b) {
    int t = blockIdx.x * blockDim.x + threadIdx.x;
    if (t < 8192) {           // w1: 64 oc x 128 k
        int oc = t >> 7, k = t & 127, c = k & 31, d = k >> 5;
        w1b[t] = (__bf16)w1[oc * 128 + c * 4 + d];
    }
    if (t < 32768) {          // w2: 128 oc x 256 k
        int oc = t >> 8, k = t & 255, c = k & 63, d = k >> 6;
        w2b[t] = (__bf16)w2[oc * 256 + c * 4 + d];
    }
}

// ---------------- stats0 via 9x9 second-moment matrix (channel-independent) ----------------
__global__ __launch_bounds__(256) void k_stats0(const float* __restrict__ x,
                                                float* __restrict__ part0) {
    __shared__ float sred[4 * 54];
    const int tid = threadIdx.x;
    float a[54];
#pragma unroll
    for (int i = 0; i < 54; i++) a[i] = 0.f;
    const int total = BSZ * 784;
    for (int p = blockIdx.x * 256 + tid; p < total; p += gridDim.x * 256) {
        int b = p / 784, pix = p - b * 784;
        int y = pix / 28, xx = pix - y * 28;
        const float* xb = x + (long)b * 784;
        float nv[9];
#pragma unroll
        for (int dy = 0; dy < 3; dy++) {
            int yy = y + dy - 1;
#pragma unroll
            for (int dx = 0; dx < 3; dx++) {
                int x2 = xx + dx - 1;
                nv[dy * 3 + dx] = (yy >= 0 && yy < 28 && x2 >= 0 && x2 < 28) ? xb[yy * 28 + x2] : 0.f;
            }
        }
        int idx = 0;
#pragma unroll
        for (int t = 0; t < 9; t++) {
            float vt = nv[t];
            a[45 + t] += vt;
#pragma unroll
            for (int u = t; u < 9; u++) { a[idx] += vt * nv[u]; idx++; }
        }
    }
#pragma unroll
    for (int i = 0; i < 54; i++) {
        float v = a[i];
        v += __shfl_xor(v, 1);  v += __shfl_xor(v, 2);  v += __shfl_xor(v, 4);
        v += __shfl_xor(v, 8);  v += __shfl_xor(v, 16); v += __shfl_xor(v, 32);
        a[i] = v;
    }
    const int l = tid & 63, w = tid >> 6;
    if (l == 0) {
#pragma unroll
        for (int i = 0; i < 54; i++) sred[w * 54 + i] = a[i];
    }
    __syncthreads();
    if (tid < 54)
        part0[blockIdx.x * 64 + tid] = sred[tid] + sred[54 + tid] + sred[108 + tid] + sred[162 + tid];
}

// finalize BN0 and fold into conv0 weights: abc0[pg*72 + tap*8 + j] = A0[c]*w0[c][tap],
// abc0[288 + c] = C0[c]  (c = pg*8 + j)
__global__ void k_fin0(const float* __restrict__ part0, const float* __restrict__ w0,
                       const float* __restrict__ g0, const float* __restrict__ be0,
                       float* __restrict__ abc0) {
    __shared__ float red[4 * 54];
    int t = threadIdx.x, c = t & 63, g = t >> 6;
    if (c < 54) {
        float acc = 0.f;
        for (int i = g; i < 1024; i += 4) acc += part0[i * 64 + c];
        red[g * 54 + c] = acc;
    }
    __syncthreads();
    if (t < 54) red[t] = red[t] + red[54 + t] + red[108 + t] + red[162 + t];
    __syncthreads();
    if (t < 32) {
        float wv[9];
#pragma unroll
        for (int tap = 0; tap < 9; tap++) wv[tap] = w0[t * 9 + tap];
        float sum = 0.f, sq = 0.f;
        int idx = 0;
#pragma unroll
        for (int ta = 0; ta < 9; ta++) {
            sum = fmaf(wv[ta], red[45 + ta], sum);
#pragma unroll
            for (int u = ta; u < 9; u++) {
                float coef = (u == ta) ? 1.f : 2.f;
                sq = fmaf(coef * wv[ta] * wv[u], red[idx], sq);
                idx++;
            }
        }
        float cnt = (float)BSZ * 784.f;
        float mean = sum / cnt;
        float var = sq / cnt - mean * mean;
        float A = g0[t] * rsqrtf(var + 1e-5f);
#pragma unroll
        for (int tap = 0; tap < 9; tap++)
            abc0[(t >> 3) * 72 + tap * 8 + (t & 7)] = A * wv[tap];
        abc0[288 + t] = be0[t] - mean * A;
    }
}

// ---------------- fused conv0(+BN0 folded)+ReLU + MFMA conv1, streamed 16-row tiles ----------------
__global__ __launch_bounds__(256) void k_conv01(const float* __restrict__ x,
                                                const float* __restrict__ abc0,
                                                const __bf16* __restrict__ w1b,
                                                __bf16* __restrict__ h1,
                                                float* __restrict__ part1) {
    __shared__ float xs[30 * 30];     // zero-padded input
    __shared__ __attribute__((aligned(16))) __bf16 sAt[2][16 * 136];
    const int b = blockIdx.x, tid = threadIdx.x;
    // zero border (116 cells)
    if (tid < 116) {
        int idx;
        if (tid < 30)      idx = tid;
        else if (tid < 60) idx = 29 * 30 + (tid - 30);
        else if (tid < 88) idx = (tid - 60 + 1) * 30;
        else               idx = (tid - 88 + 1) * 30 + 29;
        xs[idx] = 0.f;
    }
    for (int j = tid; j < 784; j += 256) {
        int yy = j / 28, xx2 = j - yy * 28;
        xs[(yy + 1) * 30 + xx2 + 1] = x[(long)b * 784 + j];
    }
    // hoisted folded weights (wave-uniform -> scalar regs)
    const int pgu = __builtin_amdgcn_readfirstlane(tid >> 6);
    const float* wfp = abc0 + pgu * 72;
    float wf[72];
#pragma unroll
    for (int i = 0; i < 72; i++) wf[i] = wfp[i];
    float c0r[8];
#pragma unroll
    for (int j = 0; j < 8; j++) c0r[j] = abc0[288 + pgu * 8 + j];

    // producer indices
    const int pi = tid & 15, pd = (tid >> 4) & 3;
    // consumer indices
    const int w = tid >> 6, l = tid & 63, q = l >> 4, n = l & 15;
    const int oc = w * 16 + n;
    bf16x8 fbv[4];
#pragma unroll
    for (int kc = 0; kc < 4; kc++)
        fbv[kc] = *(const bf16x8*)&w1b[oc * 128 + kc * 32 + q * 8];
    float ssum = 0.f, ssq = 0.f;
    __bf16* hb = h1 + (long)b * 12544 + (q * 4) * 64 + oc;
    __syncthreads();

    for (int mt = 0; mt < 13; mt++) {
        // ---- produce tile mt into sAt[mt&1] ----
        __bf16* dst = &sAt[mt & 1][pi * 136 + pd * 32 + pgu * 8];
        int m = mt * 16 + pi;
        bf16x8 pk;
        if (m < 196) {
            int my = m / 14, mx = m - my * 14;
            int y0 = my * 2 + (pd >> 1), x0 = mx * 2 + (pd & 1);
            float nv[9];
#pragma unroll
            for (int dy = 0; dy < 3; dy++)
#pragma unroll
                for (int dx = 0; dx < 3; dx++)
                    nv[dy * 3 + dx] = xs[(y0 + dy) * 30 + x0 + dx];
            float a[8];
#pragma unroll
            for (int j = 0; j < 8; j++) a[j] = c0r[j];
#pragma unroll
            for (int t = 0; t < 9; t++) {
                float nvt = nv[t];
#pragma unroll
                for (int j = 0; j < 8; j++) a[j] = fmaf(nvt, wf[t * 8 + j], a[j]);
            }
#pragma unroll
            for (int j = 0; j < 8; j++) pk[j] = (__bf16)fmaxf(a[j], 0.f);
        } else {
#pragma unroll
            for (int j = 0; j < 8; j++) pk[j] = (__bf16)0.0f;
        }
        *(bf16x8*)dst = pk;
        __syncthreads();
        // ---- consume tile mt ----
        const __bf16* sa = &sAt[mt & 1][n * 136 + q * 8];
        f32x4 acc = {0.f, 0.f, 0.f, 0.f};
#pragma unroll
        for (int kc = 0; kc < 4; kc++) {
            bf16x8 fav = *(const bf16x8*)&sa[kc * 32];
            acc = __builtin_amdgcn_mfma_f32_16x16x32_bf16(fav, fbv[kc], acc, 0, 0, 0);
        }
        bool valid = (mt < 12) | (q == 0);
        __bf16* hp = hb + mt * 16 * 64;
#pragma unroll
        for (int r = 0; r < 4; r++) {
            __bf16 hv = (__bf16)acc[r];
            if (valid) hp[r * 64] = hv;
            float fv = (float)hv;               // padded rows give 0 -> no stat effect
            ssum += fv; ssq += fv * fv;
        }
    }
    ssum += __shfl_xor(ssum, 16); ssum += __shfl_xor(ssum, 32);
    ssq  += __shfl_xor(ssq, 16);  ssq  += __shfl_xor(ssq, 32);
    if (l < 16) {
        part1[(long)oc * BSZ + b] = ssum;
        part1[(long)(64 + oc) * BSZ + b] = ssq;
    }
}

// ---------------- fused per-channel column reduce + BN finalize ----------------
// block c: sums part[c][:] and part[C+c][:], then writes abc[c], abc[C+c]
__global__ __launch_bounds__(256) void k_redfin(const float* __restrict__ part,
                                                const float* __restrict__ g,
                                                const float* __restrict__ be,
                                                float* __restrict__ abc,
                                                int C, float cnt) {
    __shared__ float s1[256], s2[256];
    const int c = blockIdx.x, tid = threadIdx.x;
    float a = 0.f, bq = 0.f;
    const float* p1 = part + (long)c * BSZ;
    const float* p2 = part + (long)(C + c) * BSZ;
    for (int i = tid; i < BSZ; i += 256) { a += p1[i]; bq += p2[i]; }
    s1[tid] = a; s2[tid] = bq;
    __syncthreads();
    for (int s = 128; s > 0; s >>= 1) {
        if (tid < s) { s1[tid] += s1[tid + s]; s2[tid] += s2[tid + s]; }
        __syncthreads();
    }
    if (tid == 0) {
        float mean = s1[0] / cnt;
        float var = s2[0] / cnt - mean * mean;
        float A = g[c] * rsqrtf(var + 1e-5f);
        abc[c] = A;
        abc[C + c] = be[c] - mean * A;
    }
}

// ---------------- conv2 MFMA (BN1+ReLU on load), streamed 16-row tiles -> z2 (aliased) + stats2 ----------------
// tile: 16 m2-rows x 256 k, LDS stride 264 (528B). Double-buffered, one barrier/tile.
// alias safety per tile: writes(mt) at elem < (mt+1)*2048; loads(mt+1) at elem >= 3584/7168/10752.
__global__ __launch_bounds__(256) void k_conv2s(__bf16* __restrict__ h1,
                                                const __bf16* __restrict__ w2b,
                                                const float* __restrict__ abc1,
                                                float* __restrict__ part2) {
    __shared__ __attribute__((aligned(16))) __bf16 sAt[2][16 * 264];
    __shared__ float sbn1[128];
    const int b = blockIdx.x, tid = threadIdx.x;
    if (tid < 128) sbn1[tid] = abc1[tid];
    const __bf16* src = h1 + (long)b * 12544;
    const int w = tid >> 6, l = tid & 63, q = l >> 4, n = l & 15;
    bf16x8 fbv[2][8];
#pragma unroll
    for (int ntl = 0; ntl < 2; ntl++) {
        int oc = (2 * w + ntl) * 16 + n;
#pragma unroll
        for (int kc = 0; kc < 8; kc++)
            fbv[ntl][kc] = *(const bf16x8*)&w2b[oc * 256 + kc * 32 + q * 8];
    }
    float ssum[2] = {0.f, 0.f}, ssq[2] = {0.f, 0.f};
    __bf16* zb = h1 + (long)b * 12544 + (q * 4) * 128 + (2 * w) * 16 + n;
    __syncthreads();   // sbn1 ready

    for (int mt = 0; mt < 4; mt++) {
        // ---- produce tile mt into sAt[mt&1]: 512 chunks, 2 per thread ----
#pragma unroll
        for (int it = 0; it < 2; it++) {
            int idx = it * 256 + tid;
            int rl = idx >> 5, o = (idx & 31) * 8;
            int r = mt * 16 + rl;
            bf16x8 wv;
            if (r < 49) {
                int d = o >> 6, c = o & 63;
                int py = r / 7, px = r - py * 7;
                int msrc = (2 * py + (d >> 1)) * 14 + 2 * px + (d & 1);
                bf16x8 v = *(const bf16x8*)&src[msrc * 64 + c];
#pragma unroll
                for (int j = 0; j < 8; j++) {
                    float f = fmaxf((float)v[j] * sbn1[c + j] + sbn1[64 + c + j], 0.f);
                    wv[j] = (__bf16)f;
                }
            } else {
#pragma unroll
                for (int j = 0; j < 8; j++) wv[j] = (__bf16)0.0f;
            }
            *(bf16x8*)&sAt[mt & 1][rl * 264 + o] = wv;
        }
        __syncthreads();
        // ---- consume tile mt ----
        bf16x8 fav[8];
#pragma unroll
        for (int kc = 0; kc < 8; kc++)
            fav[kc] = *(const bf16x8*)&sAt[mt & 1][n * 264 + kc * 32 + q * 8];
#pragma unroll
        for (int ntl = 0; ntl < 2; ntl++) {
            f32x4 acc = {0.f, 0.f, 0.f, 0.f};
#pragma unroll
            for (int kc = 0; kc < 8; kc++)
                acc = __builtin_amdgcn_mfma_f32_16x16x32_bf16(fav[kc], fbv[ntl][kc], acc, 0, 0, 0);
            __bf16* zp = zb + mt * 16 * 128 + ntl * 16;
#pragma unroll
            for (int rr = 0; rr < 4; rr++) {
                __bf16 hv = (__bf16)acc[rr];
                int m = mt * 16 + q * 4 + rr;
                if (m < 49) zp[rr * 128] = hv;
                float fv = (float)hv;           // padded rows -> 0
                ssum[ntl] += fv; ssq[ntl] += fv * fv;
            }
        }
    }
#pragma unroll
    for (int ntl = 0; ntl < 2; ntl++) {
        ssum[ntl] += __shfl_xor(ssum[ntl], 16); ssum[ntl] += __shfl_xor(ssum[ntl], 32);
        ssq[ntl]  += __shfl_xor(ssq[ntl], 16);  ssq[ntl]  += __shfl_xor(ssq[ntl], 32);
    }
    if (l < 16) {
#pragma unroll
        for (int ntl = 0; ntl < 2; ntl++) {
            int oc = (2 * w + ntl) * 16 + l;
            part2[(long)oc * BSZ + b] = ssum[ntl];
            part2[(long)(128 + oc) * BSZ + b] = ssq[ntl];
        }
    }
}

// ---------------- light epilogue: BN2 + ReLU + avgpool + FC from z2 ----------------
__global__ __launch_bounds__(256) void k_final(const __bf16* __restrict__ z2,
                                               const float* __restrict__ abc2,
                                               const float* __restrict__ wfc,
                                               const float* __restrict__ bfc,
                                               float* __restrict__ out) {
    __shared__ float sbn2[256];
    __shared__ float pp[16 * 128];
    __shared__ float pooled[128];
    __shared__ float fcred[80];
    const int b = blockIdx.x, tid = threadIdx.x;
    sbn2[tid] = abc2[tid];
    __syncthreads();
    const int g = tid & 15, c0 = g * 8, rg = tid >> 4;
    const __bf16* src = z2 + (long)b * 12544;
    float acc[8];
#pragma unroll
    for (int q = 0; q < 8; q++) acc[q] = 0.f;
    for (int rr = rg; rr < 49; rr += 16) {
        bf16x8 v = *(const bf16x8*)&src[rr * 128 + c0];
#pragma unroll
        for (int q = 0; q < 8; q++) {
            float f = fmaxf((float)v[q] * sbn2[c0 + q] + sbn2[128 + c0 + q], 0.f);
            acc[q] += f;
        }
    }
    *(f32x4*)&pp[rg * 128 + c0]     = *(f32x4*)&acc[0];
    *(f32x4*)&pp[rg * 128 + c0 + 4] = *(f32x4*)&acc[4];
    __syncthreads();
    if (tid < 128) {
        float s = 0.f;
#pragma unroll
        for (int r = 0; r < 16; r++) s += pp[r * 128 + tid];
        pooled[tid] = s * (1.f / 49.f);
    }
    __syncthreads();
    if (tid < 80) {
        int o = tid >> 3, s = tid & 7;
        float a = 0.f;
#pragma unroll
        for (int j = 0; j < 16; j++) a = fmaf(pooled[s * 16 + j], wfc[o * 128 + s * 16 + j], a);
        fcred[tid] = a;
    }
    __syncthreads();
    if (tid < 10) {
        float a = bfc[tid];
#pragma unroll
        for (int s = 0; s < 8; s++) a += fcred[tid * 8 + s];
        out[(long)b * 10 + tid] = a;
    }
}

extern "C" void kernel_launch(void* const* d_in, const int* in_sizes, int n_in,
                              void* d_out, int out_size, void* d_ws, size_t ws_size,
                              hipStream_t stream) {
    const float* x   = (const float*)d_in[0];
    const float* w0  = (const float*)d_in[1];
    const float* g0  = (const float*)d_in[3];
    const float* be0 = (const float*)d_in[4];
    const float* w1  = (const float*)d_in[5];
    const float* g1  = (const float*)d_in[7];
    const float* be1 = (const float*)d_in[8];
    const float* w2  = (const float*)d_in[9];
    const float* g2  = (const float*)d_in[11];
    const float* be2 = (const float*)d_in[12];
    const float* wfc = (const float*)d_in[13];
    const float* bfc = (const float*)d_in[14];
    float* out = (float*)d_out;

    float* ws    = (float*)d_ws;
    float* part0 = ws;                       // 1024*64
    float* abc0  = part0 + 1024 * 64;        // 320 (folded w + C0)
    float* part1 = abc0 + 320;               // 128*8192
    float* abc1  = part1 + 128 * BSZ;        // 128
    float* part2 = abc1 + 128;               // 256*8192
    float* abc2  = part2 + 256 * BSZ;        // 256
    __bf16* w1b  = (__bf16*)(abc2 + 256);    // 8192
    __bf16* w2b  = w1b + 8192;               // 32768
    __bf16* h1   = w2b + 32768;              // 8192*12544 bf16 (~205 MB); z2 aliased per-image

    k_prep<<<dim3(128), dim3(256), 0, stream>>>(w1, w2, w1b, w2b);
    k_stats0<<<dim3(1024), dim3(256), 0, stream>>>(x, part0);
    k_fin0<<<dim3(1), dim3(256), 0, stream>>>(part0, w0, g0, be0, abc0);
    k_conv01<<<dim3(BSZ), dim3(256), 0, stream>>>(x, abc0, w1b, h1, part1);
    k_redfin<<<dim3(64), dim3(256), 0, stream>>>(part1, g1, be1, abc1, 64, (float)(BSZ * 196));
    k_conv2s<<<dim3(BSZ), dim3(256), 0, stream>>>(h1, w2b, abc1, part2);
    k_redfin<<<dim3(128), dim3(256), 0, stream>>>(part2, g2, be2, abc2, 128, (float)(BSZ * 49));
    k_final<<<dim3(BSZ), dim3(256), 0, stream>>>(h1, abc2, wfc, bfc, out);
}

// Round 8
// 410.117 us; speedup vs baseline: 1.3019x; 1.0515x over previous
//
#include <hip/hip_runtime.h>
#include <hip/hip_bf16.h>

typedef __bf16 bf16x8 __attribute__((ext_vector_type(8)));
typedef float  f32x4  __attribute__((ext_vector_type(4)));

#define BSZ 8192

// ---------------- stats0 (9x9 second-moment) + weight prep merged ----------------
// prep: w1 -> w1b [64 oc][128 k], w2 -> w2b [128 oc][256 k], k = d*C + c
__global__ __launch_bounds__(256) void k_stats0(const float* __restrict__ x,
                                                float* __restrict__ part0,
                                                const float* __restrict__ w1,
                                                const float* __restrict__ w2,
                                                __bf16* __restrict__ w1b,
                                                __bf16* __restrict__ w2b) {
    __shared__ float sred[4 * 54];
    const int tid = threadIdx.x;
    {   // merged prep (first 128 blocks' thread-range)
        int t = blockIdx.x * 256 + tid;
        if (t < 8192) {           // w1: 64 oc x 128 k
            int oc = t >> 7, k = t & 127, c = k & 31, d = k >> 5;
            w1b[t] = (__bf16)w1[oc * 128 + c * 4 + d];
        }
        if (t < 32768) {          // w2: 128 oc x 256 k
            int oc = t >> 8, k = t & 255, c = k & 63, d = k >> 6;
            w2b[t] = (__bf16)w2[oc * 256 + c * 4 + d];
        }
    }
    float a[54];
#pragma unroll
    for (int i = 0; i < 54; i++) a[i] = 0.f;
    const int total = BSZ * 784;
    for (int p = blockIdx.x * 256 + tid; p < total; p += gridDim.x * 256) {
        int b = p / 784, pix = p - b * 784;
        int y = pix / 28, xx = pix - y * 28;
        const float* xb = x + (long)b * 784;
        float nv[9];
#pragma unroll
        for (int dy = 0; dy < 3; dy++) {
            int yy = y + dy - 1;
#pragma unroll
            for (int dx = 0; dx < 3; dx++) {
                int x2 = xx + dx - 1;
                nv[dy * 3 + dx] = (yy >= 0 && yy < 28 && x2 >= 0 && x2 < 28) ? xb[yy * 28 + x2] : 0.f;
            }
        }
        int idx = 0;
#pragma unroll
        for (int t2 = 0; t2 < 9; t2++) {
            float vt = nv[t2];
            a[45 + t2] += vt;
#pragma unroll
            for (int u = t2; u < 9; u++) { a[idx] += vt * nv[u]; idx++; }
        }
    }
#pragma unroll
    for (int i = 0; i < 54; i++) {
        float v = a[i];
        v += __shfl_xor(v, 1);  v += __shfl_xor(v, 2);  v += __shfl_xor(v, 4);
        v += __shfl_xor(v, 8);  v += __shfl_xor(v, 16); v += __shfl_xor(v, 32);
        a[i] = v;
    }
    const int l = tid & 63, w = tid >> 6;
    if (l == 0) {
#pragma unroll
        for (int i = 0; i < 54; i++) sred[w * 54 + i] = a[i];
    }
    __syncthreads();
    if (tid < 54)
        part0[blockIdx.x * 64 + tid] = sred[tid] + sred[54 + tid] + sred[108 + tid] + sred[162 + tid];
}

// finalize BN0 and fold into conv0 weights: abc0[pg*72 + tap*8 + j] = A0[c]*w0[c][tap],
// abc0[288 + c] = C0[c]  (c = pg*8 + j)
__global__ void k_fin0(const float* __restrict__ part0, const float* __restrict__ w0,
                       const float* __restrict__ g0, const float* __restrict__ be0,
                       float* __restrict__ abc0) {
    __shared__ float red[4 * 54];
    int t = threadIdx.x, c = t & 63, g = t >> 6;
    if (c < 54) {
        float acc = 0.f;
        for (int i = g; i < 1024; i += 4) acc += part0[i * 64 + c];
        red[g * 54 + c] = acc;
    }
    __syncthreads();
    if (t < 54) red[t] = red[t] + red[54 + t] + red[108 + t] + red[162 + t];
    __syncthreads();
    if (t < 32) {
        float wv[9];
#pragma unroll
        for (int tap = 0; tap < 9; tap++) wv[tap] = w0[t * 9 + tap];
        float sum = 0.f, sq = 0.f;
        int idx = 0;
#pragma unroll
        for (int ta = 0; ta < 9; ta++) {
            sum = fmaf(wv[ta], red[45 + ta], sum);
#pragma unroll
            for (int u = ta; u < 9; u++) {
                float coef = (u == ta) ? 1.f : 2.f;
                sq = fmaf(coef * wv[ta] * wv[u], red[idx], sq);
                idx++;
            }
        }
        float cnt = (float)BSZ * 784.f;
        float mean = sum / cnt;
        float var = sq / cnt - mean * mean;
        float A = g0[t] * rsqrtf(var + 1e-5f);
#pragma unroll
        for (int tap = 0; tap < 9; tap++)
            abc0[(t >> 3) * 72 + tap * 8 + (t & 7)] = A * wv[tap];
        abc0[288 + t] = be0[t] - mean * A;
    }
}

// ---------------- fused conv0(+BN0 folded)+ReLU + MFMA conv1, streamed tiles, 4 images/block ----------------
__global__ __launch_bounds__(256) void k_conv01(const float* __restrict__ x,
                                                const float* __restrict__ abc0,
                                                const __bf16* __restrict__ w1b,
                                                __bf16* __restrict__ h1,
                                                float* __restrict__ part1) {
    __shared__ float xs[30 * 30];     // zero-padded input
    __shared__ __attribute__((aligned(16))) __bf16 sAt[2][16 * 136];
    const int tid = threadIdx.x;
    // zero border (116 cells), once — interior overwritten per image, border stays 0
    if (tid < 116) {
        int idx;
        if (tid < 30)      idx = tid;
        else if (tid < 60) idx = 29 * 30 + (tid - 30);
        else if (tid < 88) idx = (tid - 60 + 1) * 30;
        else               idx = (tid - 88 + 1) * 30 + 29;
        xs[idx] = 0.f;
    }
    // hoisted folded weights (wave-uniform -> scalar regs)
    const int pgu = __builtin_amdgcn_readfirstlane(tid >> 6);
    const float* wfp = abc0 + pgu * 72;
    float wf[72];
#pragma unroll
    for (int i = 0; i < 72; i++) wf[i] = wfp[i];
    float c0r[8];
#pragma unroll
    for (int j = 0; j < 8; j++) c0r[j] = abc0[288 + pgu * 8 + j];

    // producer indices
    const int pi = tid & 15, pd = (tid >> 4) & 3;
    // consumer indices
    const int w = tid >> 6, l = tid & 63, q = l >> 4, n = l & 15;
    const int oc = w * 16 + n;
    bf16x8 fbv[4];
#pragma unroll
    for (int kc = 0; kc < 4; kc++)
        fbv[kc] = *(const bf16x8*)&w1b[oc * 128 + kc * 32 + q * 8];

    for (int img = 0; img < 4; img++) {
        const int b = blockIdx.x * 4 + img;
        // stage interior (prev image's consumers all passed last barrier before reaching here... barrier below protects)
        for (int j = tid; j < 784; j += 256) {
            int yy = j / 28, xx2 = j - yy * 28;
            xs[(yy + 1) * 30 + xx2 + 1] = x[(long)b * 784 + j];
        }
        __syncthreads();   // xs ready; also epoch-separates sAt reuse across images
        float ssum = 0.f, ssq = 0.f;
        __bf16* hb = h1 + (long)b * 12544 + (q * 4) * 64 + oc;
        for (int mt = 0; mt < 13; mt++) {
            // ---- produce tile mt into sAt[mt&1] ----
            __bf16* dst = &sAt[mt & 1][pi * 136 + pd * 32 + pgu * 8];
            int m = mt * 16 + pi;
            bf16x8 pk;
            if (m < 196) {
                int my = m / 14, mx = m - my * 14;
                int y0 = my * 2 + (pd >> 1), x0 = mx * 2 + (pd & 1);
                float nv[9];
#pragma unroll
                for (int dy = 0; dy < 3; dy++)
#pragma unroll
                    for (int dx = 0; dx < 3; dx++)
                        nv[dy * 3 + dx] = xs[(y0 + dy) * 30 + x0 + dx];
                float a[8];
#pragma unroll
                for (int j = 0; j < 8; j++) a[j] = c0r[j];
#pragma unroll
                for (int t = 0; t < 9; t++) {
                    float nvt = nv[t];
#pragma unroll
                    for (int j = 0; j < 8; j++) a[j] = fmaf(nvt, wf[t * 8 + j], a[j]);
                }
#pragma unroll
                for (int j = 0; j < 8; j++) pk[j] = (__bf16)fmaxf(a[j], 0.f);
            } else {
#pragma unroll
                for (int j = 0; j < 8; j++) pk[j] = (__bf16)0.0f;
            }
            *(bf16x8*)dst = pk;
            __syncthreads();
            // ---- consume tile mt ----
            const __bf16* sa = &sAt[mt & 1][n * 136 + q * 8];
            f32x4 acc = {0.f, 0.f, 0.f, 0.f};
#pragma unroll
            for (int kc = 0; kc < 4; kc++) {
                bf16x8 fav = *(const bf16x8*)&sa[kc * 32];
                acc = __builtin_amdgcn_mfma_f32_16x16x32_bf16(fav, fbv[kc], acc, 0, 0, 0);
            }
            bool valid = (mt < 12) | (q == 0);
            __bf16* hp = hb + mt * 16 * 64;
#pragma unroll
            for (int r = 0; r < 4; r++) {
                __bf16 hv = (__bf16)acc[r];
                if (valid) hp[r * 64] = hv;
                float fv = (float)hv;               // padded rows give 0 -> no stat effect
                ssum += fv; ssq += fv * fv;
            }
        }
        ssum += __shfl_xor(ssum, 16); ssum += __shfl_xor(ssum, 32);
        ssq  += __shfl_xor(ssq, 16);  ssq  += __shfl_xor(ssq, 32);
        if (l < 16) {
            part1[(long)oc * BSZ + b] = ssum;
            part1[(long)(64 + oc) * BSZ + b] = ssq;
        }
    }
}

// ---------------- fused per-channel column reduce + BN finalize ----------------
__global__ __launch_bounds__(256) void k_redfin(const float* __restrict__ part,
                                                const float* __restrict__ g,
                                                const float* __restrict__ be,
                                                float* __restrict__ abc,
                                                int C, float cnt) {
    __shared__ float s1[256], s2[256];
    const int c = blockIdx.x, tid = threadIdx.x;
    float a = 0.f, bq = 0.f;
    const float* p1 = part + (long)c * BSZ;
    const float* p2 = part + (long)(C + c) * BSZ;
    for (int i = tid; i < BSZ; i += 256) { a += p1[i]; bq += p2[i]; }
    s1[tid] = a; s2[tid] = bq;
    __syncthreads();
    for (int s = 128; s > 0; s >>= 1) {
        if (tid < s) { s1[tid] += s1[tid + s]; s2[tid] += s2[tid + s]; }
        __syncthreads();
    }
    if (tid == 0) {
        float mean = s1[0] / cnt;
        float var = s2[0] / cnt - mean * mean;
        float A = g[c] * rsqrtf(var + 1e-5f);
        abc[c] = A;
        abc[C + c] = be[c] - mean * A;
    }
}

// ---------------- conv2 MFMA (BN1+ReLU on load), streamed tiles, 4 images/block ----------------
// z2 stores bounced through LDS (zt, stride 136) -> coalesced bf16x8 row stores.
// alias safety per tile mt: z2 writes at elem < (mt+1)*2048; produce(mt+1) loads at elem >= 3584/7168/10752.
__global__ __launch_bounds__(256) void k_conv2s(__bf16* __restrict__ h1,
                                                const __bf16* __restrict__ w2b,
                                                const float* __restrict__ abc1,
                                                float* __restrict__ part2) {
    __shared__ __attribute__((aligned(16))) __bf16 sAt[2][16 * 264];
    __shared__ __attribute__((aligned(16))) __bf16 zt[16 * 136];
    __shared__ float sbn1[128];
    const int tid = threadIdx.x;
    if (tid < 128) sbn1[tid] = abc1[tid];
    const int w = tid >> 6, l = tid & 63, q = l >> 4, n = l & 15;
    bf16x8 fbv[2][8];
#pragma unroll
    for (int ntl = 0; ntl < 2; ntl++) {
        int oc = (2 * w + ntl) * 16 + n;
#pragma unroll
        for (int kc = 0; kc < 8; kc++)
            fbv[ntl][kc] = *(const bf16x8*)&w2b[oc * 256 + kc * 32 + q * 8];
    }
    __syncthreads();   // sbn1 ready

    for (int img = 0; img < 4; img++) {
        const int b = blockIdx.x * 4 + img;
        __bf16* src = h1 + (long)b * 12544;
        float ssum[2] = {0.f, 0.f}, ssq[2] = {0.f, 0.f};
        for (int mt = 0; mt < 4; mt++) {
            // ---- produce tile mt into sAt[mt&1]: 512 chunks, 2 per thread ----
#pragma unroll
            for (int it = 0; it < 2; it++) {
                int idx = it * 256 + tid;
                int rl = idx >> 5, o = (idx & 31) * 8;
                int r = mt * 16 + rl;
                bf16x8 wv;
                if (r < 49) {
                    int d = o >> 6, c = o & 63;
                    int py = r / 7, px = r - py * 7;
                    int msrc = (2 * py + (d >> 1)) * 14 + 2 * px + (d & 1);
                    bf16x8 v = *(const bf16x8*)&src[msrc * 64 + c];
#pragma unroll
                    for (int j = 0; j < 8; j++) {
                        float f = fmaxf((float)v[j] * sbn1[c + j] + sbn1[64 + c + j], 0.f);
                        wv[j] = (__bf16)f;
                    }
                } else {
#pragma unroll
                    for (int j = 0; j < 8; j++) wv[j] = (__bf16)0.0f;
                }
                *(bf16x8*)&sAt[mt & 1][rl * 264 + o] = wv;
            }
            __syncthreads();   // B1: tile ready (also: all prior zt reads precede this in program order)
            // ---- consume tile mt: MFMA -> zt + stats ----
            bf16x8 fav[8];
#pragma unroll
            for (int kc = 0; kc < 8; kc++)
                fav[kc] = *(const bf16x8*)&sAt[mt & 1][n * 264 + kc * 32 + q * 8];
#pragma unroll
            for (int ntl = 0; ntl < 2; ntl++) {
                f32x4 acc = {0.f, 0.f, 0.f, 0.f};
#pragma unroll
                for (int kc = 0; kc < 8; kc++)
                    acc = __builtin_amdgcn_mfma_f32_16x16x32_bf16(fav[kc], fbv[ntl][kc], acc, 0, 0, 0);
#pragma unroll
                for (int rr = 0; rr < 4; rr++) {
                    __bf16 hv = (__bf16)acc[rr];
                    zt[(q * 4 + rr) * 136 + (2 * w + ntl) * 16 + n] = hv;
                    float fv = (float)hv;           // padded rows -> 0
                    ssum[ntl] += fv; ssq[ntl] += fv * fv;
                }
            }
            __syncthreads();   // B2: zt complete
            // ---- coalesced z2 store: 16 rows x 128 oc, one bf16x8 per thread ----
            {
                int row = tid >> 4, o = (tid & 15) * 8;
                int m = mt * 16 + row;
                if (m < 49) {
                    bf16x8 zv = *(const bf16x8*)&zt[row * 136 + o];
                    *(bf16x8*)&src[m * 128 + o] = zv;
                }
            }
        }
#pragma unroll
        for (int ntl = 0; ntl < 2; ntl++) {
            ssum[ntl] += __shfl_xor(ssum[ntl], 16); ssum[ntl] += __shfl_xor(ssum[ntl], 32);
            ssq[ntl]  += __shfl_xor(ssq[ntl], 16);  ssq[ntl]  += __shfl_xor(ssq[ntl], 32);
        }
        if (l < 16) {
#pragma unroll
            for (int ntl = 0; ntl < 2; ntl++) {
                int oc = (2 * w + ntl) * 16 + l;
                part2[(long)oc * BSZ + b] = ssum[ntl];
                part2[(long)(128 + oc) * BSZ + b] = ssq[ntl];
            }
        }
    }
}

// ---------------- light epilogue: BN2 + ReLU + avgpool + FC from z2, 4 images/block ----------------
__global__ __launch_bounds__(256) void k_final(const __bf16* __restrict__ z2,
                                               const float* __restrict__ abc2,
                                               const float* __restrict__ wfc,
                                               const float* __restrict__ bfc,
                                               float* __restrict__ out) {
    __shared__ float sbn2[256];
    __shared__ float pp[16 * 128];
    __shared__ float pooled[128];
    __shared__ float fcred[80];
    const int tid = threadIdx.x;
    sbn2[tid] = abc2[tid];
    __syncthreads();
    const int g = tid & 15, c0 = g * 8, rg = tid >> 4;
    for (int img = 0; img < 4; img++) {
        const int b = blockIdx.x * 4 + img;
        const __bf16* src = z2 + (long)b * 12544;
        float acc[8];
#pragma unroll
        for (int q = 0; q < 8; q++) acc[q] = 0.f;
        for (int rr = rg; rr < 49; rr += 16) {
            bf16x8 v = *(const bf16x8*)&src[rr * 128 + c0];
#pragma unroll
            for (int q = 0; q < 8; q++) {
                float f = fmaxf((float)v[q] * sbn2[c0 + q] + sbn2[128 + c0 + q], 0.f);
                acc[q] += f;
            }
        }
        *(f32x4*)&pp[rg * 128 + c0]     = *(f32x4*)&acc[0];
        *(f32x4*)&pp[rg * 128 + c0 + 4] = *(f32x4*)&acc[4];
        __syncthreads();
        if (tid < 128) {
            float s = 0.f;
#pragma unroll
            for (int r = 0; r < 16; r++) s += pp[r * 128 + tid];
            pooled[tid] = s * (1.f / 49.f);
        }
        __syncthreads();
        if (tid < 80) {
            int o = tid >> 3, s = tid & 7;
            float a = 0.f;
#pragma unroll
            for (int j = 0; j < 16; j++) a = fmaf(pooled[s * 16 + j], wfc[o * 128 + s * 16 + j], a);
            fcred[tid] = a;
        }
        __syncthreads();
        if (tid < 10) {
            float a = bfc[tid];
#pragma unroll
            for (int s = 0; s < 8; s++) a += fcred[tid * 8 + s];
            out[(long)b * 10 + tid] = a;
        }
    }
}

extern "C" void kernel_launch(void* const* d_in, const int* in_sizes, int n_in,
                              void* d_out, int out_size, void* d_ws, size_t ws_size,
                              hipStream_t stream) {
    const float* x   = (const float*)d_in[0];
    const float* w0  = (const float*)d_in[1];
    const float* g0  = (const float*)d_in[3];
    const float* be0 = (const float*)d_in[4];
    const float* w1  = (const float*)d_in[5];
    const float* g1  = (const float*)d_in[7];
    const float* be1 = (const float*)d_in[8];
    const float* w2  = (const float*)d_in[9];
    const float* g2  = (const float*)d_in[11];
    const float* be2 = (const float*)d_in[12];
    const float* wfc = (const float*)d_in[13];
    const float* bfc = (const float*)d_in[14];
    float* out = (float*)d_out;

    float* ws    = (float*)d_ws;
    float* part0 = ws;                       // 1024*64
    float* abc0  = part0 + 1024 * 64;        // 320 (folded w + C0)
    float* part1 = abc0 + 320;               // 128*8192
    float* abc1  = part1 + 128 * BSZ;        // 128
    float* part2 = abc1 + 128;               // 256*8192
    float* abc2  = part2 + 256 * BSZ;        // 256
    __bf16* w1b  = (__bf16*)(abc2 + 256);    // 8192
    __bf16* w2b  = w1b + 8192;               // 32768
    __bf16* h1   = w2b + 32768;              // 8192*12544 bf16 (~205 MB); z2 aliased per-image

    k_stats0<<<dim3(1024), dim3(256), 0, stream>>>(x, part0, w1, w2, w1b, w2b);
    k_fin0<<<dim3(1), dim3(256), 0, stream>>>(part0, w0, g0, be0, abc0);
    k_conv01<<<dim3(BSZ / 4), dim3(256), 0, stream>>>(x, abc0, w1b, h1, part1);
    k_redfin<<<dim3(64), dim3(256), 0, stream>>>(part1, g1, be1, abc1, 64, (float)(BSZ * 196));
    k_conv2s<<<dim3(BSZ / 4), dim3(256), 0, stream>>>(h1, w2b, abc1, part2);
    k_redfin<<<dim3(128), dim3(256), 0, stream>>>(part2, g2, be2, abc2, 128, (float)(BSZ * 49));
    k_final<<<dim3(BSZ / 4), dim3(256), 0, stream>>>(h1, abc2, wfc, bfc, out);
}